// Round 8
// baseline (350.530 us; speedup 1.0000x reference)
//
#include <hip/hip_runtime.h>
#include <hip/hip_bf16.h>
#include <hip/hip_fp16.h>

// ---------------------------------------------------------------------------
// 2-layer GAT (PyG GATConv semantics).
// Round 8: aggregate inner loop rewritten for ~2x fewer VALU inst/edge:
//  - 4 lanes/edge (16 ch each, 2x16B loads) -> per-edge overhead halved,
//    16 edges in flight per wave.
//  - edge-pair processing with v_perm + v_dot2_f32_f16 (fdot2): 1 perm +
//    1 dot per (2ch x 2edges) instead of 4 cvt + 4 fma. f32 accumulate.
//  - uniform-base + 32-bit voffset addressing for the h16 gathers.
// Everything else as round 7 (MFMA split-bf16 GEMM w/ fused scores, f16 h
// table, head-partitioned XCD-affine blocks, fused output head).
// ---------------------------------------------------------------------------

#define HEADS 4
#define CDIM 64
#define HC 256  // HEADS*CDIM

typedef __attribute__((ext_vector_type(8))) short bf16x8;   // 8 bf16 = 4 VGPR
typedef __attribute__((ext_vector_type(4))) float f32x4;    // MFMA acc
typedef _Float16 __attribute__((ext_vector_type(2))) f16x2;

#if __has_builtin(__builtin_amdgcn_fdot2) && \
    __has_builtin(__builtin_amdgcn_cvt_pkrtz) && \
    __has_builtin(__builtin_amdgcn_perm)
#define USE_FDOT2 1
#else
#define USE_FDOT2 0
#endif

__device__ __forceinline__ short f32_to_bf16_rne(float v) {
  unsigned u = __float_as_uint(v);
  unsigned r = (u + 0x7FFFu + ((u >> 16) & 1u)) >> 16;
  return (short)r;
}
__device__ __forceinline__ float bf16_bits_to_f32(short s) {
  return __uint_as_float(((unsigned)(unsigned short)s) << 16);
}

// -------- one-time weight pack: W[K][256] f32 -> Wt_hi/Wt_lo [256][K] bf16 --
__global__ __launch_bounds__(256) void pack_w_kernel(
    const float* __restrict__ W, short* __restrict__ Wt_hi,
    short* __restrict__ Wt_lo, int K, int total) {
  const int i = blockIdx.x * 256 + threadIdx.x;
  if (i >= total) return;
  const int k = i >> 8, n = i & 255;   // N fixed = 256
  const float v = W[i];
  const short hi = f32_to_bf16_rne(v);
  const short lo = f32_to_bf16_rne(v - bf16_bits_to_f32(hi));
  Wt_hi[(size_t)n * K + k] = hi;
  Wt_lo[(size_t)n * K + k] = lo;
}

// ---------------- split-bf16 MFMA GEMM: h = A[M,K] @ W[K,256] --------------
// block = 128 thr (2 waves); wave w: cols col0 = by*128 + w*64 (one head).
// Epilogue: h16[M,256] f16 write + fused a_s/a_d (quad shfl reduction).
__global__ __launch_bounds__(128) void gemm_mfma_split(
    const float* __restrict__ A, const short* __restrict__ Wt_hi,
    const short* __restrict__ Wt_lo, __half* __restrict__ h16,
    const float* __restrict__ att_s, const float* __restrict__ att_d,
    float* __restrict__ a_s, float* __restrict__ a_d, int M, int K) {
  __shared__ alignas(16) short As_hi[64 * 32];
  __shared__ alignas(16) short As_lo[64 * 32];
  const int t = threadIdx.x;
  const int wave = t >> 6;
  const int lane = t & 63;
  const int quad = lane >> 4;
  const int m16 = lane & 15;
  const int row0 = blockIdx.x * 64;
  const int col0 = blockIdx.y * 128 + wave * 64;   // == head*64
  const int head = col0 >> 6;

  f32x4 acc[4][4] = {};  // [mt][nt]

  for (int k0 = 0; k0 < K; k0 += 32) {
    if (k0) __syncthreads();
#pragma unroll
    for (int uu = 0; uu < 2; ++uu) {
      const int u = t + uu * 128;       // 0..255
      const int r = u >> 2, seg = u & 3;
      const int gr = row0 + r;
      float vv[8] = {0.f, 0.f, 0.f, 0.f, 0.f, 0.f, 0.f, 0.f};
      if (gr < M) {
        const float* ap = A + (size_t)gr * K + k0 + seg * 8;
        const float4 v0 = *(const float4*)ap;
        const float4 v1 = *(const float4*)(ap + 4);
        vv[0] = v0.x; vv[1] = v0.y; vv[2] = v0.z; vv[3] = v0.w;
        vv[4] = v1.x; vv[5] = v1.y; vv[6] = v1.z; vv[7] = v1.w;
      }
      bf16x8 h8, l8;
#pragma unroll
      for (int j = 0; j < 8; ++j) {
        const short hi = f32_to_bf16_rne(vv[j]);
        h8[j] = hi;
        l8[j] = f32_to_bf16_rne(vv[j] - bf16_bits_to_f32(hi));
      }
      *(bf16x8*)(As_hi + r * 32 + seg * 8) = h8;
      *(bf16x8*)(As_lo + r * 32 + seg * 8) = l8;
    }
    bf16x8 b_hi[4], b_lo[4];
#pragma unroll
    for (int nt = 0; nt < 4; ++nt) {
      const size_t off = (size_t)(col0 + nt * 16 + m16) * K + k0 + quad * 8;
      b_hi[nt] = *(const bf16x8*)(Wt_hi + off);
      b_lo[nt] = *(const bf16x8*)(Wt_lo + off);
    }
    __syncthreads();
    bf16x8 a_hi[4], a_lo[4];
#pragma unroll
    for (int mt = 0; mt < 4; ++mt) {
      const int off = (mt * 16 + m16) * 32 + quad * 8;
      a_hi[mt] = *(const bf16x8*)(As_hi + off);
      a_lo[mt] = *(const bf16x8*)(As_lo + off);
    }
#pragma unroll
    for (int mt = 0; mt < 4; ++mt)
#pragma unroll
      for (int nt = 0; nt < 4; ++nt) {
        acc[mt][nt] = __builtin_amdgcn_mfma_f32_16x16x32_bf16(
            a_hi[mt], b_hi[nt], acc[mt][nt], 0, 0, 0);
        acc[mt][nt] = __builtin_amdgcn_mfma_f32_16x16x32_bf16(
            a_hi[mt], b_lo[nt], acc[mt][nt], 0, 0, 0);
        acc[mt][nt] = __builtin_amdgcn_mfma_f32_16x16x32_bf16(
            a_lo[mt], b_hi[nt], acc[mt][nt], 0, 0, 0);
      }
  }
  float sa[4], da[4];
#pragma unroll
  for (int nt = 0; nt < 4; ++nt) {
    sa[nt] = att_s[col0 + nt * 16 + m16];
    da[nt] = att_d[col0 + nt * 16 + m16];
  }
#pragma unroll
  for (int mt = 0; mt < 4; ++mt)
#pragma unroll
    for (int r = 0; r < 4; ++r) {
      const int gr = row0 + mt * 16 + quad * 4 + r;
      float ps = acc[mt][0][r] * sa[0] + acc[mt][1][r] * sa[1] +
                 acc[mt][2][r] * sa[2] + acc[mt][3][r] * sa[3];
      float pd = acc[mt][0][r] * da[0] + acc[mt][1][r] * da[1] +
                 acc[mt][2][r] * da[2] + acc[mt][3][r] * da[3];
#pragma unroll
      for (int off = 1; off <= 8; off <<= 1) {
        ps += __shfl_xor(ps, off);
        pd += __shfl_xor(pd, off);
      }
      if (gr < M) {
        if (m16 == 0) {
          a_s[gr * HEADS + head] = ps;
          a_d[gr * HEADS + head] = pd;
        }
#pragma unroll
        for (int nt = 0; nt < 4; ++nt)
          h16[(size_t)gr * HC + col0 + nt * 16 + m16] =
              __float2half(acc[mt][nt][r]);
      }
    }
}

// ======================= CSR construction (per call) =======================
__global__ __launch_bounds__(256) void deg_count_kernel(
    const int* __restrict__ dst, int* __restrict__ deg, int E_raw, int Etot) {
  const int e = blockIdx.x * 256 + threadIdx.x;
  if (e >= Etot) return;
  const int d = (e < E_raw) ? dst[e] : (e - E_raw);
  atomicAdd(&deg[d], 1);
}

__global__ __launch_bounds__(256) void scan_block_kernel(
    const int* __restrict__ deg, int* __restrict__ incl,
    int* __restrict__ bsum, int N) {
  __shared__ int sm[256];
  const int t = threadIdx.x;
  const int i = blockIdx.x * 256 + t;
  int v = (i < N) ? deg[i] : 0;
  sm[t] = v;
  __syncthreads();
#pragma unroll
  for (int off = 1; off < 256; off <<= 1) {
    int x = (t >= off) ? sm[t - off] : 0;
    __syncthreads();
    sm[t] += x;
    __syncthreads();
  }
  if (i < N) incl[i] = sm[t];
  if (t == 255) bsum[blockIdx.x] = sm[255];
}

__global__ __launch_bounds__(256) void scan_top_kernel(
    const int* __restrict__ bsum, int* __restrict__ boff, int nb) {
  __shared__ int sm[256];
  const int t = threadIdx.x;
  int v = (t < nb) ? bsum[t] : 0;
  sm[t] = v;
  __syncthreads();
#pragma unroll
  for (int off = 1; off < 256; off <<= 1) {
    int x = (t >= off) ? sm[t - off] : 0;
    __syncthreads();
    sm[t] += x;
    __syncthreads();
  }
  if (t < nb) boff[t] = sm[t] - v;  // exclusive
}

__global__ __launch_bounds__(256) void scan_final_kernel(
    const int* __restrict__ deg, const int* __restrict__ incl,
    const int* __restrict__ boff, int* __restrict__ row_ptr,
    int* __restrict__ cursor, int N, int Etot) {
  const int i = blockIdx.x * 256 + threadIdx.x;
  if (i == 0) row_ptr[N] = Etot;
  if (i >= N) return;
  const int v = boff[blockIdx.x] + incl[i] - deg[i];
  row_ptr[i] = v;
  cursor[i] = v;
}

__global__ __launch_bounds__(256) void csr_scatter_kernel(
    const int* __restrict__ src, const int* __restrict__ dst,
    int* __restrict__ cursor, int* __restrict__ csr_src, int E_raw, int Etot) {
  const int e = blockIdx.x * 256 + threadIdx.x;
  if (e >= Etot) return;
  const int s = (e < E_raw) ? src[e] : (e - E_raw);
  const int d = (e < E_raw) ? dst[e] : (e - E_raw);
  const int pos = atomicAdd(&cursor[d], 1);
  csr_src[pos] = s;
}

// ================= fused softmax + aggregation (f16 gather) ================
// grid = N blocks. block b: head hd = b&3 (XCD-affine), nodes 4*(b>>2)..+3
// (wave = node). lane: es = lane>>2 edge slot (16 slots, pair-unrolled),
// cs = lane&3 -> 16 channels (2 x 16B loads).
__device__ __forceinline__ void fma16_f16(float ex, const uint4& A,
                                          const uint4& B, float* acc) {
  const __half2* hp0 = (const __half2*)&A;
  const __half2* hp1 = (const __half2*)&B;
#pragma unroll
  for (int j = 0; j < 4; ++j) {
    float2 f = __half22float2(hp0[j]);
    acc[2 * j] += ex * f.x;
    acc[2 * j + 1] += ex * f.y;
  }
#pragma unroll
  for (int j = 0; j < 4; ++j) {
    float2 f = __half22float2(hp1[j]);
    acc[8 + 2 * j] += ex * f.x;
    acc[8 + 2 * j + 1] += ex * f.y;
  }
}

__global__ __launch_bounds__(256) void gat_aggregate_kernel(
    const int* __restrict__ row_ptr, const int* __restrict__ csr_src,
    const __half* __restrict__ h16, const float* __restrict__ a_s,
    const float* __restrict__ a_d, const float* __restrict__ b,
    float* __restrict__ out, int mode) {
  const int bid = blockIdx.x;
  const int hd = bid & 3;
  const int n = (bid >> 2) * 4 + (threadIdx.x >> 6);
  const int lane = threadIdx.x & 63;
  const int es = lane >> 2;          // edge slot 0..15
  const int cs = lane & 3;           // channel segment (16 ch)
  const float ad = a_d[n * HEADS + hd];
  const int beg = row_ptr[n];
  const int end = row_ptr[n + 1];
  const char* hb = (const char*)h16 + hd * 128;   // uniform base
  const unsigned csoff = (unsigned)cs << 5;       // 32B per segment
  const float* asb = a_s + hd;
  float acc[16];
#pragma unroll
  for (int k = 0; k < 16; ++k) acc[k] = 0.f;
  float den = 0.f;
  int i = beg + es;
  // ---- edge-pair main loop ----
  for (; i + 16 < end; i += 32) {
    const int s0 = csr_src[i];
    const int s1 = csr_src[i + 16];
    const float as0 = asb[s0 * 4];
    const float as1 = asb[s1 * 4];
    const unsigned off0 = ((unsigned)s0 << 9) + csoff;
    const unsigned off1 = ((unsigned)s1 << 9) + csoff;
    const uint4 ua0 = *(const uint4*)(hb + off0);
    const uint4 ua1 = *(const uint4*)(hb + off0 + 16);
    const uint4 ub0 = *(const uint4*)(hb + off1);
    const uint4 ub1 = *(const uint4*)(hb + off1 + 16);
    float t0 = as0 + ad; t0 = fmaxf(t0, 0.2f * t0);
    float t1 = as1 + ad; t1 = fmaxf(t1, 0.2f * t1);
    const float e0 = __expf(t0);
    const float e1 = __expf(t1);
    den += e0 + e1;
#if USE_FDOT2
    const f16x2 exh = __builtin_bit_cast(
        f16x2, __builtin_amdgcn_cvt_pkrtz(e0, e1));
#define DOT2STEP(u0r, u1r, k)                                                 \
    {                                                                         \
      const unsigned lo_ = __builtin_amdgcn_perm(u1r, u0r, 0x05040100u);      \
      const unsigned hi_ = __builtin_amdgcn_perm(u1r, u0r, 0x07060302u);      \
      acc[k] = __builtin_amdgcn_fdot2(exh, __builtin_bit_cast(f16x2, lo_),    \
                                      acc[k], false);                         \
      acc[k + 1] = __builtin_amdgcn_fdot2(                                    \
          exh, __builtin_bit_cast(f16x2, hi_), acc[k + 1], false);            \
    }
    DOT2STEP(ua0.x, ub0.x, 0)
    DOT2STEP(ua0.y, ub0.y, 2)
    DOT2STEP(ua0.z, ub0.z, 4)
    DOT2STEP(ua0.w, ub0.w, 6)
    DOT2STEP(ua1.x, ub1.x, 8)
    DOT2STEP(ua1.y, ub1.y, 10)
    DOT2STEP(ua1.z, ub1.z, 12)
    DOT2STEP(ua1.w, ub1.w, 14)
#undef DOT2STEP
#else
    fma16_f16(e0, ua0, ua1, acc);
    fma16_f16(e1, ub0, ub1, acc);
#endif
  }
  // ---- remainder (single edges) ----
  for (; i < end; i += 16) {
    const int s = csr_src[i];
    float t0 = asb[s * 4] + ad;
    t0 = fmaxf(t0, 0.2f * t0);
    const float ex = __expf(t0);
    den += ex;
    const unsigned off = ((unsigned)s << 9) + csoff;
    const uint4 u0 = *(const uint4*)(hb + off);
    const uint4 u1 = *(const uint4*)(hb + off + 16);
    fma16_f16(ex, u0, u1, acc);
  }
  // ---- reduce across 16 edge slots (lane bits 2..5) ----
#pragma unroll
  for (int off = 4; off <= 32; off <<= 1) {
#pragma unroll
    for (int k = 0; k < 16; ++k) acc[k] += __shfl_xor(acc[k], off);
    den += __shfl_xor(den, off);
  }
  if (lane < 4) {
    const float inv = 1.f / den;
    float u[16];
#pragma unroll
    for (int k = 0; k < 16; ++k) u[k] = acc[k] * inv;
    if (mode == 0) {
      const float* bb = b + hd * CDIM + cs * 16;
#pragma unroll
      for (int k = 0; k < 16; ++k) {
        const float t0 = u[k] + bb[k];
        u[k] = (t0 > 0.f) ? t0 : (__expf(t0) - 1.f);
      }
    }
    float* op = out + (size_t)n * HC + hd * CDIM + cs * 16;
#pragma unroll
    for (int k = 0; k < 4; ++k)
      *(float4*)(op + 4 * k) =
          make_float4(u[4 * k], u[4 * k + 1], u[4 * k + 2], u[4 * k + 3]);
  }
}

// ---- fused output head: out[n,:] = (mean_h agg[n,h,:] + b2) @ Wout + bout --
__global__ __launch_bounds__(256) void final_fused_kernel(
    const float* __restrict__ agg, const float* __restrict__ b2,
    const float* __restrict__ Wout, const float* __restrict__ bout,
    float* __restrict__ out, int N) {
  const int n = blockIdx.x * 4 + (threadIdx.x >> 6);
  const int c = threadIdx.x & 63;
  if (n >= N) return;
  const float* ar = agg + (size_t)n * HC;
  const float m = 0.25f * (ar[c] + ar[c + 64] + ar[c + 128] + ar[c + 192]) +
                  b2[c];
  const float4* wr = (const float4*)(Wout + c * 16);
  const float4 w0 = wr[0], w1 = wr[1], w2 = wr[2], w3 = wr[3];
  float p[16] = {m * w0.x, m * w0.y, m * w0.z, m * w0.w,
                 m * w1.x, m * w1.y, m * w1.z, m * w1.w,
                 m * w2.x, m * w2.y, m * w2.z, m * w2.w,
                 m * w3.x, m * w3.y, m * w3.z, m * w3.w};
#pragma unroll
  for (int off = 1; off < 64; off <<= 1)
#pragma unroll
    for (int j = 0; j < 16; ++j) p[j] += __shfl_xor(p[j], off);
  if (c == 0) {
    float* op = out + (size_t)n * 16;
    *(float4*)op = make_float4(p[0] + bout[0], p[1] + bout[1],
                               p[2] + bout[2], p[3] + bout[3]);
    *(float4*)(op + 4) = make_float4(p[4] + bout[4], p[5] + bout[5],
                                     p[6] + bout[6], p[7] + bout[7]);
    *(float4*)(op + 8) = make_float4(p[8] + bout[8], p[9] + bout[9],
                                     p[10] + bout[10], p[11] + bout[11]);
    *(float4*)(op + 12) = make_float4(p[12] + bout[12], p[13] + bout[13],
                                      p[14] + bout[14], p[15] + bout[15]);
  }
}

extern "C" void kernel_launch(void* const* d_in, const int* in_sizes, int n_in,
                              void* d_out, int out_size, void* d_ws, size_t ws_size,
                              hipStream_t stream) {
  const float* x      = (const float*)d_in[0];
  const int*   eidx   = (const int*)d_in[1];
  const float* W1     = (const float*)d_in[2];
  const float* att_s1 = (const float*)d_in[3];
  const float* att_d1 = (const float*)d_in[4];
  const float* b1     = (const float*)d_in[5];
  const float* W2     = (const float*)d_in[6];
  const float* att_s2 = (const float*)d_in[7];
  const float* att_d2 = (const float*)d_in[8];
  const float* b2     = (const float*)d_in[9];
  const float* Wout   = (const float*)d_in[10];
  const float* bout   = (const float*)d_in[11];
  float* out          = (float*)d_out;

  const int N     = in_sizes[0] / 128;   // 20000
  const int E_raw = in_sizes[1] / 2;     // 640000
  const int Etot  = E_raw + N;           // + self loops
  const int* src = eidx;
  const int* dst = eidx + E_raw;
  const int NB = (N + 255) / 256;        // 79 scan blocks

  // ---- workspace layout ----
  float* ws = (float*)d_ws;
  float* buf_agg = ws;                          // [N,256] agg1/ELU out, agg2
  float* buf_as  = buf_agg + (size_t)N * HC;    // [N,4]
  float* buf_ad  = buf_as + (size_t)N * HEADS;  // [N,4]
  __half* h16    = (__half*)(buf_ad + (size_t)N * HEADS);  // [N,256] f16
  int* deg     = (int*)(h16 + (size_t)N * HC);  // [N]
  int* incl    = deg + N;
  int* row_ptr = incl + N;                      // [N+1]
  int* cursor  = row_ptr + (N + 1);
  int* bsum    = cursor + N;                    // [NB]
  int* boff    = bsum + NB;                     // [NB]
  int* csr_src = boff + NB;                     // [Etot]
  uintptr_t wp = ((uintptr_t)(csr_src + Etot) + 15) & ~(uintptr_t)15;
  short* wt1_hi = (short*)wp;                   // [256][128]
  short* wt1_lo = wt1_hi + 256 * 128;
  short* wt2_hi = wt1_lo + 256 * 128;           // [256][256]
  short* wt2_lo = wt2_hi + 256 * 256;

  const dim3 blk(256);
  const int g_edge = (Etot + 255) / 256;
  const dim3 g_gemm((N + 63) / 64, 2);
  const dim3 blk_gemm(128);

  // ================= weight pack + CSR build =================
  pack_w_kernel<<<(128 * 256 + 255) / 256, blk, 0, stream>>>(W1, wt1_hi, wt1_lo,
                                                             128, 128 * 256);
  pack_w_kernel<<<(256 * 256 + 255) / 256, blk, 0, stream>>>(W2, wt2_hi, wt2_lo,
                                                             256, 256 * 256);
  hipMemsetAsync(deg, 0, (size_t)N * sizeof(int), stream);
  deg_count_kernel<<<g_edge, blk, 0, stream>>>(dst, deg, E_raw, Etot);
  scan_block_kernel<<<NB, blk, 0, stream>>>(deg, incl, bsum, N);
  scan_top_kernel<<<1, blk, 0, stream>>>(bsum, boff, NB);
  scan_final_kernel<<<NB, blk, 0, stream>>>(deg, incl, boff, row_ptr, cursor, N, Etot);
  csr_scatter_kernel<<<g_edge, blk, 0, stream>>>(src, dst, cursor, csr_src, E_raw, Etot);

  // ================= Layer 1 =================
  gemm_mfma_split<<<g_gemm, blk_gemm, 0, stream>>>(
      x, wt1_hi, wt1_lo, h16, att_s1, att_d1, buf_as, buf_ad, N, 128);
  gat_aggregate_kernel<<<N, blk, 0, stream>>>(row_ptr, csr_src, h16, buf_as,
                                              buf_ad, b1, buf_agg, 0);

  // ================= Layer 2 =================
  gemm_mfma_split<<<g_gemm, blk_gemm, 0, stream>>>(
      buf_agg, wt2_hi, wt2_lo, h16, att_s2, att_d2, buf_as, buf_ad, N, 256);
  gat_aggregate_kernel<<<N, blk, 0, stream>>>(row_ptr, csr_src, h16, buf_as,
                                              buf_ad, b2, buf_agg, 1);

  // ================= Output head (mean + bias + Wout fused) =================
  final_fused_kernel<<<(N + 3) / 4, blk, 0, stream>>>(buf_agg, b2, Wout, bout,
                                                      out, N);
}

// Round 9
// 323.142 us; speedup vs baseline: 1.0848x; 1.0848x over previous
//
#include <hip/hip_runtime.h>
#include <hip/hip_bf16.h>
#include <hip/hip_fp16.h>

// ---------------------------------------------------------------------------
// 2-layer GAT (PyG GATConv semantics).
// Round 9: aggregate reverted to round-7 structure (8 lanes/edge, 16B f16
// loads, pair-unrolled) with v_fma_mix_f32 inner math (1 instr per channel,
// f32 accumulate — bit-identical to cvt+fma). Scan merged into one
// single-block kernel; output head restructured to 4 nodes/wave.
// ---------------------------------------------------------------------------

#define HEADS 4
#define CDIM 64
#define HC 256  // HEADS*CDIM

typedef __attribute__((ext_vector_type(8))) short bf16x8;   // 8 bf16 = 4 VGPR
typedef __attribute__((ext_vector_type(4))) float f32x4;    // MFMA acc

__device__ __forceinline__ short f32_to_bf16_rne(float v) {
  unsigned u = __float_as_uint(v);
  unsigned r = (u + 0x7FFFu + ((u >> 16) & 1u)) >> 16;
  return (short)r;
}
__device__ __forceinline__ float bf16_bits_to_f32(short s) {
  return __uint_as_float(((unsigned)(unsigned short)s) << 16);
}

// acc_lo += f16lo(reg)*ex ; acc_hi += f16hi(reg)*ex   (f32 accumulate)
__device__ __forceinline__ void fma_mix2(float& alo, float& ahi,
                                         unsigned reg, float ex) {
  asm("v_fma_mix_f32 %0, %2, %3, %0 op_sel:[0,0,0] op_sel_hi:[1,0,0]\n\t"
      "v_fma_mix_f32 %1, %2, %3, %1 op_sel:[1,0,0] op_sel_hi:[1,0,0]"
      : "+v"(alo), "+v"(ahi)
      : "v"(reg), "v"(ex));
}
__device__ __forceinline__ void fma_mix8(float ex, const uint4& u, float* acc) {
  fma_mix2(acc[0], acc[1], u.x, ex);
  fma_mix2(acc[2], acc[3], u.y, ex);
  fma_mix2(acc[4], acc[5], u.z, ex);
  fma_mix2(acc[6], acc[7], u.w, ex);
}

// -------- one-time weight pack: W[K][256] f32 -> Wt_hi/Wt_lo [256][K] bf16 --
__global__ __launch_bounds__(256) void pack_w_kernel(
    const float* __restrict__ W, short* __restrict__ Wt_hi,
    short* __restrict__ Wt_lo, int K, int total) {
  const int i = blockIdx.x * 256 + threadIdx.x;
  if (i >= total) return;
  const int k = i >> 8, n = i & 255;   // N fixed = 256
  const float v = W[i];
  const short hi = f32_to_bf16_rne(v);
  const short lo = f32_to_bf16_rne(v - bf16_bits_to_f32(hi));
  Wt_hi[(size_t)n * K + k] = hi;
  Wt_lo[(size_t)n * K + k] = lo;
}

// ---------------- split-bf16 MFMA GEMM: h = A[M,K] @ W[K,256] --------------
// block = 128 thr (2 waves); wave w: cols col0 = by*128 + w*64 (one head).
// Epilogue: h16[M,256] f16 write + fused a_s/a_d (quad shfl reduction).
__global__ __launch_bounds__(128) void gemm_mfma_split(
    const float* __restrict__ A, const short* __restrict__ Wt_hi,
    const short* __restrict__ Wt_lo, __half* __restrict__ h16,
    const float* __restrict__ att_s, const float* __restrict__ att_d,
    float* __restrict__ a_s, float* __restrict__ a_d, int M, int K) {
  __shared__ alignas(16) short As_hi[64 * 32];
  __shared__ alignas(16) short As_lo[64 * 32];
  const int t = threadIdx.x;
  const int wave = t >> 6;
  const int lane = t & 63;
  const int quad = lane >> 4;
  const int m16 = lane & 15;
  const int row0 = blockIdx.x * 64;
  const int col0 = blockIdx.y * 128 + wave * 64;   // == head*64
  const int head = col0 >> 6;

  f32x4 acc[4][4] = {};  // [mt][nt]

  for (int k0 = 0; k0 < K; k0 += 32) {
    if (k0) __syncthreads();
#pragma unroll
    for (int uu = 0; uu < 2; ++uu) {
      const int u = t + uu * 128;       // 0..255
      const int r = u >> 2, seg = u & 3;
      const int gr = row0 + r;
      float vv[8] = {0.f, 0.f, 0.f, 0.f, 0.f, 0.f, 0.f, 0.f};
      if (gr < M) {
        const float* ap = A + (size_t)gr * K + k0 + seg * 8;
        const float4 v0 = *(const float4*)ap;
        const float4 v1 = *(const float4*)(ap + 4);
        vv[0] = v0.x; vv[1] = v0.y; vv[2] = v0.z; vv[3] = v0.w;
        vv[4] = v1.x; vv[5] = v1.y; vv[6] = v1.z; vv[7] = v1.w;
      }
      bf16x8 h8, l8;
#pragma unroll
      for (int j = 0; j < 8; ++j) {
        const short hi = f32_to_bf16_rne(vv[j]);
        h8[j] = hi;
        l8[j] = f32_to_bf16_rne(vv[j] - bf16_bits_to_f32(hi));
      }
      *(bf16x8*)(As_hi + r * 32 + seg * 8) = h8;
      *(bf16x8*)(As_lo + r * 32 + seg * 8) = l8;
    }
    bf16x8 b_hi[4], b_lo[4];
#pragma unroll
    for (int nt = 0; nt < 4; ++nt) {
      const size_t off = (size_t)(col0 + nt * 16 + m16) * K + k0 + quad * 8;
      b_hi[nt] = *(const bf16x8*)(Wt_hi + off);
      b_lo[nt] = *(const bf16x8*)(Wt_lo + off);
    }
    __syncthreads();
    bf16x8 a_hi[4], a_lo[4];
#pragma unroll
    for (int mt = 0; mt < 4; ++mt) {
      const int off = (mt * 16 + m16) * 32 + quad * 8;
      a_hi[mt] = *(const bf16x8*)(As_hi + off);
      a_lo[mt] = *(const bf16x8*)(As_lo + off);
    }
#pragma unroll
    for (int mt = 0; mt < 4; ++mt)
#pragma unroll
      for (int nt = 0; nt < 4; ++nt) {
        acc[mt][nt] = __builtin_amdgcn_mfma_f32_16x16x32_bf16(
            a_hi[mt], b_hi[nt], acc[mt][nt], 0, 0, 0);
        acc[mt][nt] = __builtin_amdgcn_mfma_f32_16x16x32_bf16(
            a_hi[mt], b_lo[nt], acc[mt][nt], 0, 0, 0);
        acc[mt][nt] = __builtin_amdgcn_mfma_f32_16x16x32_bf16(
            a_lo[mt], b_hi[nt], acc[mt][nt], 0, 0, 0);
      }
  }
  float sa[4], da[4];
#pragma unroll
  for (int nt = 0; nt < 4; ++nt) {
    sa[nt] = att_s[col0 + nt * 16 + m16];
    da[nt] = att_d[col0 + nt * 16 + m16];
  }
#pragma unroll
  for (int mt = 0; mt < 4; ++mt)
#pragma unroll
    for (int r = 0; r < 4; ++r) {
      const int gr = row0 + mt * 16 + quad * 4 + r;
      float ps = acc[mt][0][r] * sa[0] + acc[mt][1][r] * sa[1] +
                 acc[mt][2][r] * sa[2] + acc[mt][3][r] * sa[3];
      float pd = acc[mt][0][r] * da[0] + acc[mt][1][r] * da[1] +
                 acc[mt][2][r] * da[2] + acc[mt][3][r] * da[3];
#pragma unroll
      for (int off = 1; off <= 8; off <<= 1) {
        ps += __shfl_xor(ps, off);
        pd += __shfl_xor(pd, off);
      }
      if (gr < M) {
        if (m16 == 0) {
          a_s[gr * HEADS + head] = ps;
          a_d[gr * HEADS + head] = pd;
        }
#pragma unroll
        for (int nt = 0; nt < 4; ++nt)
          h16[(size_t)gr * HC + col0 + nt * 16 + m16] =
              __float2half(acc[mt][nt][r]);
      }
    }
}

// ======================= CSR construction (per call) =======================
__global__ __launch_bounds__(256) void deg_count_kernel(
    const int* __restrict__ dst, int* __restrict__ deg, int E_raw, int Etot) {
  const int e = blockIdx.x * 256 + threadIdx.x;
  if (e >= Etot) return;
  const int d = (e < E_raw) ? dst[e] : (e - E_raw);
  atomicAdd(&deg[d], 1);
}

// single-block scan: deg[N] -> exclusive row_ptr[N+1] + cursor copy.
// 1024 threads x CH contiguous elems each (CH <= 24 for N <= 24576).
__global__ __launch_bounds__(1024) void scan_all_kernel(
    const int* __restrict__ deg, int* __restrict__ row_ptr,
    int* __restrict__ cursor, int N, int Etot) {
  __shared__ int sm[1024];
  const int t = threadIdx.x;
  const int CH = (N + 1023) >> 10;
  const int base = t * CH;
  int loc[24];
  int sum = 0;
  for (int j = 0; j < CH; ++j) {
    const int idx = base + j;
    const int v = (idx < N) ? deg[idx] : 0;
    loc[j] = sum;  // exclusive within chunk
    sum += v;
  }
  sm[t] = sum;
  __syncthreads();
  for (int off = 1; off < 1024; off <<= 1) {
    const int x = (t >= off) ? sm[t - off] : 0;
    __syncthreads();
    sm[t] += x;
    __syncthreads();
  }
  const int excl = sm[t] - sum;
  for (int j = 0; j < CH; ++j) {
    const int idx = base + j;
    if (idx < N) {
      const int v = excl + loc[j];
      row_ptr[idx] = v;
      cursor[idx] = v;
    }
  }
  if (t == 0) row_ptr[N] = Etot;
}

__global__ __launch_bounds__(256) void csr_scatter_kernel(
    const int* __restrict__ src, const int* __restrict__ dst,
    int* __restrict__ cursor, int* __restrict__ csr_src, int E_raw, int Etot) {
  const int e = blockIdx.x * 256 + threadIdx.x;
  if (e >= Etot) return;
  const int s = (e < E_raw) ? src[e] : (e - E_raw);
  const int d = (e < E_raw) ? dst[e] : (e - E_raw);
  const int pos = atomicAdd(&cursor[d], 1);
  csr_src[pos] = s;
}

// ================= fused softmax + aggregation (f16 gather) ================
// grid = N blocks. block b: head hd = b&3 (XCD-affine), nodes 4*(b>>2)..+3
// (wave = node). lane: q = lane>>3 edge slot (stride 8, pair-unrolled),
// oc = lane&7 channel octet (8 f16 ch = one 16B load).
__global__ __launch_bounds__(256) void gat_aggregate_kernel(
    const int* __restrict__ row_ptr, const int* __restrict__ csr_src,
    const __half* __restrict__ h16, const float* __restrict__ a_s,
    const float* __restrict__ a_d, const float* __restrict__ b,
    float* __restrict__ out, int mode) {
  const int bid = blockIdx.x;
  const int hd = bid & 3;
  const int n = (bid >> 2) * 4 + (threadIdx.x >> 6);
  const int lane = threadIdx.x & 63;
  const int q = lane >> 3;
  const int oc = lane & 7;
  const float ad = a_d[n * HEADS + hd];
  const int beg = row_ptr[n];
  const int end = row_ptr[n + 1];
  const char* hbase = (const char*)h16 + hd * 128 + oc * 16;  // bytes
  const float* asb = a_s + hd;
  float acc[8] = {0.f, 0.f, 0.f, 0.f, 0.f, 0.f, 0.f, 0.f};
  float den = 0.f;
  int i = beg + q;
  for (; i + 8 < end; i += 16) {
    const int s0 = csr_src[i];
    const int s1 = csr_src[i + 8];
    const float as0 = asb[s0 * 4];
    const float as1 = asb[s1 * 4];
    const uint4 u0 = *(const uint4*)(hbase + ((unsigned)s0 << 9));
    const uint4 u1 = *(const uint4*)(hbase + ((unsigned)s1 << 9));
    float a0 = as0 + ad; a0 = fmaxf(a0, 0.2f * a0);
    float a1 = as1 + ad; a1 = fmaxf(a1, 0.2f * a1);
    const float e0 = __expf(a0);
    const float e1 = __expf(a1);
    den += e0 + e1;
    fma_mix8(e0, u0, acc);
    fma_mix8(e1, u1, acc);
  }
  for (; i < end; i += 8) {
    const int s = csr_src[i];
    float a = asb[s * 4] + ad;
    a = fmaxf(a, 0.2f * a);
    const float ex = __expf(a);
    den += ex;
    const uint4 u = *(const uint4*)(hbase + ((unsigned)s << 9));
    fma_mix8(ex, u, acc);
  }
  // reduce across the 8 slots (lane bits 3,4,5)
#pragma unroll
  for (int off = 8; off <= 32; off <<= 1) {
#pragma unroll
    for (int k = 0; k < 8; ++k) acc[k] += __shfl_xor(acc[k], off);
    den += __shfl_xor(den, off);
  }
  if (lane < 8) {
    const float inv = 1.f / den;
    float u[8];
#pragma unroll
    for (int k = 0; k < 8; ++k) u[k] = acc[k] * inv;
    if (mode == 0) {
      const float* bb = b + hd * CDIM + oc * 8;
#pragma unroll
      for (int k = 0; k < 8; ++k) {
        const float t0 = u[k] + bb[k];
        u[k] = (t0 > 0.f) ? t0 : (__expf(t0) - 1.f);
      }
    }
    float* op = out + (size_t)n * HC + hd * CDIM + oc * 8;
    *(float4*)op = make_float4(u[0], u[1], u[2], u[3]);
    *(float4*)(op + 4) = make_float4(u[4], u[5], u[6], u[7]);
  }
}

// ---- fused output head: out[n,:] = (mean_h agg[n,h,:] + b2) @ Wout + bout --
// 4 nodes per wave: 16 lanes/node, lane covers 4 channels; butterfly(1,2,4,8).
__global__ __launch_bounds__(256) void final_fused_kernel(
    const float* __restrict__ agg, const float* __restrict__ b2,
    const float* __restrict__ Wout, const float* __restrict__ bout,
    float* __restrict__ out, int N) {
  const int lane = threadIdx.x & 63;
  const int c4 = lane & 15;  // channel quad: channels 4*c4..+3
  const int n = blockIdx.x * 16 + (threadIdx.x >> 6) * 4 + (lane >> 4);
  if (n >= N) return;
  const float* ar = agg + (size_t)n * HC + c4 * 4;
  const float4 a0 = *(const float4*)ar;
  const float4 a1 = *(const float4*)(ar + 64);
  const float4 a2 = *(const float4*)(ar + 128);
  const float4 a3 = *(const float4*)(ar + 192);
  const float4 bb = *(const float4*)(b2 + c4 * 4);
  const float m[4] = {0.25f * (a0.x + a1.x + a2.x + a3.x) + bb.x,
                      0.25f * (a0.y + a1.y + a2.y + a3.y) + bb.y,
                      0.25f * (a0.z + a1.z + a2.z + a3.z) + bb.z,
                      0.25f * (a0.w + a1.w + a2.w + a3.w) + bb.w};
  float p[16] = {};
#pragma unroll
  for (int k = 0; k < 4; ++k) {
    const float4* wr = (const float4*)(Wout + (c4 * 4 + k) * 16);
    const float4 w0 = wr[0], w1 = wr[1], w2 = wr[2], w3 = wr[3];
    p[0] += m[k] * w0.x;  p[1] += m[k] * w0.y;
    p[2] += m[k] * w0.z;  p[3] += m[k] * w0.w;
    p[4] += m[k] * w1.x;  p[5] += m[k] * w1.y;
    p[6] += m[k] * w1.z;  p[7] += m[k] * w1.w;
    p[8] += m[k] * w2.x;  p[9] += m[k] * w2.y;
    p[10] += m[k] * w2.z; p[11] += m[k] * w2.w;
    p[12] += m[k] * w3.x; p[13] += m[k] * w3.y;
    p[14] += m[k] * w3.z; p[15] += m[k] * w3.w;
  }
#pragma unroll
  for (int off = 1; off <= 8; off <<= 1)
#pragma unroll
    for (int j = 0; j < 16; ++j) p[j] += __shfl_xor(p[j], off);
  if (c4 == 0) {
    float* op = out + (size_t)n * 16;
    *(float4*)op = make_float4(p[0] + bout[0], p[1] + bout[1],
                               p[2] + bout[2], p[3] + bout[3]);
    *(float4*)(op + 4) = make_float4(p[4] + bout[4], p[5] + bout[5],
                                     p[6] + bout[6], p[7] + bout[7]);
    *(float4*)(op + 8) = make_float4(p[8] + bout[8], p[9] + bout[9],
                                     p[10] + bout[10], p[11] + bout[11]);
    *(float4*)(op + 12) = make_float4(p[12] + bout[12], p[13] + bout[13],
                                      p[14] + bout[14], p[15] + bout[15]);
  }
}

extern "C" void kernel_launch(void* const* d_in, const int* in_sizes, int n_in,
                              void* d_out, int out_size, void* d_ws, size_t ws_size,
                              hipStream_t stream) {
  const float* x      = (const float*)d_in[0];
  const int*   eidx   = (const int*)d_in[1];
  const float* W1     = (const float*)d_in[2];
  const float* att_s1 = (const float*)d_in[3];
  const float* att_d1 = (const float*)d_in[4];
  const float* b1     = (const float*)d_in[5];
  const float* W2     = (const float*)d_in[6];
  const float* att_s2 = (const float*)d_in[7];
  const float* att_d2 = (const float*)d_in[8];
  const float* b2     = (const float*)d_in[9];
  const float* Wout   = (const float*)d_in[10];
  const float* bout   = (const float*)d_in[11];
  float* out          = (float*)d_out;

  const int N     = in_sizes[0] / 128;   // 20000
  const int E_raw = in_sizes[1] / 2;     // 640000
  const int Etot  = E_raw + N;           // + self loops
  const int* src = eidx;
  const int* dst = eidx + E_raw;

  // ---- workspace layout ----
  float* ws = (float*)d_ws;
  float* buf_agg = ws;                          // [N,256] agg1/ELU out, agg2
  float* buf_as  = buf_agg + (size_t)N * HC;    // [N,4]
  float* buf_ad  = buf_as + (size_t)N * HEADS;  // [N,4]
  __half* h16    = (__half*)(buf_ad + (size_t)N * HEADS);  // [N,256] f16
  int* deg     = (int*)(h16 + (size_t)N * HC);  // [N]
  int* row_ptr = deg + N;                       // [N+1]
  int* cursor  = row_ptr + (N + 1);             // [N]
  int* csr_src = cursor + N;                    // [Etot]
  uintptr_t wp = ((uintptr_t)(csr_src + Etot) + 15) & ~(uintptr_t)15;
  short* wt1_hi = (short*)wp;                   // [256][128]
  short* wt1_lo = wt1_hi + 256 * 128;
  short* wt2_hi = wt1_lo + 256 * 128;           // [256][256]
  short* wt2_lo = wt2_hi + 256 * 256;

  const dim3 blk(256);
  const int g_edge = (Etot + 255) / 256;
  const dim3 g_gemm((N + 63) / 64, 2);
  const dim3 blk_gemm(128);

  // ================= weight pack + CSR build =================
  pack_w_kernel<<<(128 * 256 + 255) / 256, blk, 0, stream>>>(W1, wt1_hi, wt1_lo,
                                                             128, 128 * 256);
  pack_w_kernel<<<(256 * 256 + 255) / 256, blk, 0, stream>>>(W2, wt2_hi, wt2_lo,
                                                             256, 256 * 256);
  hipMemsetAsync(deg, 0, (size_t)N * sizeof(int), stream);
  deg_count_kernel<<<g_edge, blk, 0, stream>>>(dst, deg, E_raw, Etot);
  scan_all_kernel<<<1, 1024, 0, stream>>>(deg, row_ptr, cursor, N, Etot);
  csr_scatter_kernel<<<g_edge, blk, 0, stream>>>(src, dst, cursor, csr_src, E_raw, Etot);

  // ================= Layer 1 =================
  gemm_mfma_split<<<g_gemm, blk_gemm, 0, stream>>>(
      x, wt1_hi, wt1_lo, h16, att_s1, att_d1, buf_as, buf_ad, N, 128);
  gat_aggregate_kernel<<<N, blk, 0, stream>>>(row_ptr, csr_src, h16, buf_as,
                                              buf_ad, b1, buf_agg, 0);

  // ================= Layer 2 =================
  gemm_mfma_split<<<g_gemm, blk_gemm, 0, stream>>>(
      buf_agg, wt2_hi, wt2_lo, h16, att_s2, att_d2, buf_as, buf_ad, N, 256);
  gat_aggregate_kernel<<<N, blk, 0, stream>>>(row_ptr, csr_src, h16, buf_as,
                                              buf_ad, b2, buf_agg, 1);

  // ================= Output head (mean + bias + Wout fused) =================
  final_fused_kernel<<<(N + 15) / 16, blk, 0, stream>>>(buf_agg, b2, Wout, bout,
                                                        out, N);
}